// Round 9
// baseline (167.952 us; speedup 1.0000x reference)
//
#include <hip/hip_runtime.h>
#include <hip/hip_bf16.h>

typedef float f32x4 __attribute__((ext_vector_type(4)));
typedef short s16x8 __attribute__((ext_vector_type(8)));

#define SIGC 2379
#define KPAD 2432
#define NKT  76          // KPAD/32 k-tiles
#define NKT_Q 19         // per split-K quarter
#define SROW 2440        // padded LDS row
#define NPATH 12800

// Tiled layout for A and W (bf16): element (row r, k) lives at
//   ((r>>4)*NKT + (k>>5))*512 + ((k>>3)&3)*128 + (r&15)*8 + (k&7)
// 1KB tiles of [ks(4)][R(16)][kw(8)] — fragment-ready for 16x16x32 MFMA;
// the per-lane frag offset lane*16B is LANE-LINEAR, so a tile can be read
// as a frag directly from global (L2) or staged via global_load_lds.

__device__ inline void split2(float v, __hip_bfloat16* h, __hip_bfloat16* l) {
    __hip_bfloat16 hh = __float2bfloat16(v);
    *h = hh;
    *l = __float2bfloat16(v - __bfloat162float(hh));
}

__device__ inline void gload_lds16(const __hip_bfloat16* g, __hip_bfloat16* l) {
    __builtin_amdgcn_global_load_lds(
        (const __attribute__((address_space(1))) void*)g,
        (__attribute__((address_space(3))) void*)l,
        16, 0, 0);
}

// ---------------------------------------------------------------------------
// W convert: W[256][2379] fp32 -> tiled Wh/Wl bf16 hi+lo (pad zeroed)
// ---------------------------------------------------------------------------
__global__ __launch_bounds__(256) void wconv_kernel(const float* __restrict__ W,
                                                    __hip_bfloat16* __restrict__ Wh,
                                                    __hip_bfloat16* __restrict__ Wl)
{
    int k = blockIdx.x * 256 + threadIdx.x;
    int n = blockIdx.y;
    if (k >= KPAD) return;
    float v = (k < SIGC) ? W[(size_t)n * SIGC + k] : 0.0f;
    size_t off = ((size_t)(n >> 4) * NKT + (k >> 5)) * 512 + ((k >> 3) & 3) * 128 + (n & 15) * 8 + (k & 7);
    split2(v, &Wh[off], &Wl[off]);
}

// ---------------------------------------------------------------------------
// Signature kernel: 4 waves/block, 4 pp-phases; at phase pp wave w computes
// path row = pp*4 + w, so the 4 live rows are consecutive -> cooperative
// 64B-contiguous copy-out. Register-only Chen scan; lane owns pairs
// p in {lane, lane+64, lane+128(<169)}.
// s3[ijk] += dx[k] * (s2[ij] + 0.5*dx[j]*(s1[i] + dx[i]/3))
// ---------------------------------------------------------------------------
__global__ __launch_bounds__(256) void sig_kernel(const float* __restrict__ x,
                                                  __hip_bfloat16* __restrict__ Ah,
                                                  __hip_bfloat16* __restrict__ Al_,
                                                  int r_start)
{
    __shared__ float inc_s[4][5][16];                        // [wave][step][channel]
    __shared__ __align__(16) __hip_bfloat16 hi_s[4][SROW];   // [wave] = row 4*pp+w
    __shared__ __align__(16) __hip_bfloat16 lo_s[4][SROW];

    const int t = threadIdx.x;
    const int w = t >> 6;
    const int lane = t & 63;

    const int p0 = lane;
    const int p1 = lane + 64;
    const int p2 = lane + 128;
    const bool has2 = (p2 < 169);
    const int i0 = p0 / 13, j0 = p0 - i0 * 13;
    const int i1 = p1 / 13, j1 = p1 - i1 * 13;
    const int i2 = p2 / 13, j2 = p2 - i2 * 13;   // used under has2

    for (int pp = 0; pp < 4; ++pp) {
        const int r = r_start + blockIdx.x * 16 + pp * 4 + w;
        const int nn = r & 7;
        const int jj = (r >> 3) & 63;
        const int ii = r >> 9;

        __syncthreads();   // guard inc_s / hi_s / lo_s reuse across pp
        if (lane < 13) {
            if (lane < 12) {
                const float* px = x + ((size_t)(nn * 12 + lane) * 1600 + ii * 64 + jj) * 5;
                float prev = 0.0f;
                #pragma unroll
                for (int l = 0; l < 5; ++l) {
                    float v = px[l];
                    inc_s[w][l][lane] = v - prev;
                    prev = v;
                }
            } else {
                inc_s[w][0][12] = 0.0f;
                #pragma unroll
                for (int l = 1; l < 5; ++l) inc_s[w][l][12] = 0.25f;
            }
        }
        __syncthreads();

        float s1i0 = 0.0f, s1i1 = 0.0f, s1i2 = 0.0f;
        float s2p0 = 0.0f, s2p1 = 0.0f, s2p2 = 0.0f;
        float s1own = 0.0f;
        float s3a[13], s3b[13], s3c[13];
        #pragma unroll
        for (int k = 0; k < 13; ++k) { s3a[k] = 0.0f; s3b[k] = 0.0f; s3c[k] = 0.0f; }

        for (int l = 0; l < 5; ++l) {
            float dxl[13];
            #pragma unroll
            for (int k = 0; k < 13; ++k) dxl[k] = inc_s[w][l][k];

            {   // pair 0
                float dxi = inc_s[w][l][i0];
                float dxj = inc_s[w][l][j0];
                float C   = s2p0 + 0.5f * dxj * (s1i0 + dxi * (1.0f / 3.0f));
                #pragma unroll
                for (int k = 0; k < 13; ++k) s3a[k] += dxl[k] * C;
                s2p0 += s1i0 * dxj + 0.5f * dxi * dxj;
                s1i0 += dxi;
            }
            {   // pair 1
                float dxi = inc_s[w][l][i1];
                float dxj = inc_s[w][l][j1];
                float C   = s2p1 + 0.5f * dxj * (s1i1 + dxi * (1.0f / 3.0f));
                #pragma unroll
                for (int k = 0; k < 13; ++k) s3b[k] += dxl[k] * C;
                s2p1 += s1i1 * dxj + 0.5f * dxi * dxj;
                s1i1 += dxi;
            }
            if (has2) {   // pair 2
                float dxi = inc_s[w][l][i2];
                float dxj = inc_s[w][l][j2];
                float C   = s2p2 + 0.5f * dxj * (s1i2 + dxi * (1.0f / 3.0f));
                #pragma unroll
                for (int k = 0; k < 13; ++k) s3c[k] += dxl[k] * C;
                s2p2 += s1i2 * dxj + 0.5f * dxi * dxj;
                s1i2 += dxi;
            }
            if (lane < 13) s1own += inc_s[w][l][lane];
        }

        // ---- write sig row into this wave's LDS row (hi/lo) ----
        if (lane < 13) split2(s1own, &hi_s[w][lane], &lo_s[w][lane]);
        split2(s2p0, &hi_s[w][13 + p0], &lo_s[w][13 + p0]);
        split2(s2p1, &hi_s[w][13 + p1], &lo_s[w][13 + p1]);
        if (has2) split2(s2p2, &hi_s[w][13 + p2], &lo_s[w][13 + p2]);
        #pragma unroll
        for (int k = 0; k < 13; ++k) split2(s3a[k], &hi_s[w][182 + p0 * 13 + k], &lo_s[w][182 + p0 * 13 + k]);
        #pragma unroll
        for (int k = 0; k < 13; ++k) split2(s3b[k], &hi_s[w][182 + p1 * 13 + k], &lo_s[w][182 + p1 * 13 + k]);
        if (has2) {
            #pragma unroll
            for (int k = 0; k < 13; ++k) split2(s3c[k], &hi_s[w][182 + p2 * 13 + k], &lo_s[w][182 + p2 * 13 + k]);
        }
        if (lane < KPAD - SIGC) {   // zero pad 2379..2431
            hi_s[w][SIGC + lane] = __float2bfloat16(0.0f);
            lo_s[w][SIGC + lane] = __float2bfloat16(0.0f);
        }

        __syncthreads();   // all 4 rows complete before cooperative copy-out

        // ---- block-cooperative coalesced copy-out (64B bursts) ----
        const int rtl = blockIdx.x;
        const int rr = t & 3, ks = (t >> 2) & 3, ts = t >> 4;
        #pragma unroll
        for (int it2 = 0; it2 < 5; ++it2) {
            int kt = it2 * 16 + ts;
            if (kt < NKT) {
                size_t off = ((size_t)rtl * NKT + kt) * 512 + ks * 128 + (pp * 4 + rr) * 8;
                int lidx = kt * 32 + ks * 8;
                *reinterpret_cast<int4*>(Ah + off)  = *reinterpret_cast<const int4*>(&hi_s[rr][lidx]);
                *reinterpret_cast<int4*>(Al_ + off) = *reinterpret_cast<const int4*>(&lo_s[rr][lidx]);
            }
        }
    }
}

// ---------------------------------------------------------------------------
// Split-bf16 GEMM, BM=64 x BN=256 (full N), split-K=4:
// P[ksp][m][o] = sum_{k in quarter} AhWh + AhWl + AlWh   (fp32 partials)
// A staged in LDS (16 KB dbuf, gload_lds). W frags read directly from
// global (L2-hot, ksp->XCD pinned) but PREFETCHED ONE K-TILE AHEAD into
// named double-buffered registers (bh0/bl0 <-> bh1/bl1) so the L2 latency
// hides under the current tile's 48 MFMAs; the barrier's vmcnt(0) drain
// guarantees arrival. 4 waves, each 64x64 = 4x4 frags.
// bid = k2*8 + ksp*2 + b, mIdx = k2*2 + b (bid%8 pins ksp to an XCD slot).
// ---------------------------------------------------------------------------
__global__ __launch_bounds__(256) void gemm_kernel(const __hip_bfloat16* __restrict__ Ah,
                                                   const __hip_bfloat16* __restrict__ Al_,
                                                   const __hip_bfloat16* __restrict__ Wh,
                                                   const __hip_bfloat16* __restrict__ Wl,
                                                   float* __restrict__ P,
                                                   int chunk_alloc, int nmblk)
{
    __shared__ __align__(16) __hip_bfloat16 L[2][8 * 512];   // 16 KB: Ah tiles 0-3, Al 4-7

    const int bid = blockIdx.x;
    const int x8 = bid & 7;
    const int ksp = x8 >> 1;
    const int bb = x8 & 1;
    const int k2 = bid >> 3;
    const int mIdx = k2 * 2 + bb;
    if (mIdx >= nmblk) return;

    const int t = threadIdx.x;
    const int lane = t & 63;
    const int w = t >> 6;
    const int rt0 = mIdx * 4;        // 4 m-row-tiles
    const int kt0 = ksp * NKT_Q;

    f32x4 acc[4][4] = {};

    // wave w stages A row-tile w (hi and lo)
    auto stage = [&](int buf, int kt) {
        gload_lds16(Ah  + ((size_t)(rt0 + w) * NKT + kt) * 512 + lane * 8, &L[buf][w * 512]);
        gload_lds16(Al_ + ((size_t)(rt0 + w) * NKT + kt) * 512 + lane * 8, &L[buf][(4 + w) * 512]);
    };

    // wave w's B column tiles (n-tiles w*4..w*4+3), lane-linear 1KB reads
    auto loadB = [&](int kt, s16x8* bh, s16x8* bl) {
        #pragma unroll
        for (int nn = 0; nn < 4; ++nn) {
            const size_t wo = ((size_t)(w * 4 + nn) * NKT + kt) * 512 + lane * 8;
            bh[nn] = *reinterpret_cast<const s16x8*>(Wh + wo);
            bl[nn] = *reinterpret_cast<const s16x8*>(Wl + wo);
        }
    };

    auto compute = [&](int lb, const s16x8* bh, const s16x8* bl) {
        s16x8 ah[4], al4[4];
        #pragma unroll
        for (int mm = 0; mm < 4; ++mm) {
            ah[mm]  = *reinterpret_cast<const s16x8*>(&L[lb][mm * 512 + lane * 8]);
            al4[mm] = *reinterpret_cast<const s16x8*>(&L[lb][(4 + mm) * 512 + lane * 8]);
        }
        #pragma unroll
        for (int nn = 0; nn < 4; ++nn)
            #pragma unroll
            for (int mm = 0; mm < 4; ++mm) {
                acc[mm][nn] = __builtin_amdgcn_mfma_f32_16x16x32_bf16(ah[mm],  bh[nn], acc[mm][nn], 0, 0, 0);
                acc[mm][nn] = __builtin_amdgcn_mfma_f32_16x16x32_bf16(ah[mm],  bl[nn], acc[mm][nn], 0, 0, 0);
                acc[mm][nn] = __builtin_amdgcn_mfma_f32_16x16x32_bf16(al4[mm], bh[nn], acc[mm][nn], 0, 0, 0);
            }
    };

    s16x8 bh0[4], bl0[4], bh1[4], bl1[4];
    loadB(kt0, bh0, bl0);
    stage(0, kt0);
    int cur = 0;
    __syncthreads();

    int kk = 0;
    #pragma unroll 1
    for (;;) {
        // even step: consume set 0, prefetch set 1
        if (kk + 1 < NKT_Q) { stage(cur ^ 1, kt0 + kk + 1); loadB(kt0 + kk + 1, bh1, bl1); }
        compute(cur, bh0, bl0);
        __syncthreads();
        cur ^= 1; ++kk;
        if (kk == NKT_Q) break;
        // odd step: consume set 1, prefetch set 0
        if (kk + 1 < NKT_Q) { stage(cur ^ 1, kt0 + kk + 1); loadB(kt0 + kk + 1, bh0, bl0); }
        compute(cur, bh1, bl1);
        __syncthreads();
        cur ^= 1; ++kk;
        if (kk == NKT_Q) break;
    }

    // ---- epilogue: coalesced fp32 partial stores ----
    // C/D layout: col=lane&15, row=(lane>>4)*4+reg
    float* Pb = P + ((size_t)ksp * chunk_alloc + mIdx * 64) * 256;
    #pragma unroll
    for (int mm = 0; mm < 4; ++mm)
        #pragma unroll
        for (int nn = 0; nn < 4; ++nn) {
            int o = w * 64 + nn * 16 + (lane & 15);
            #pragma unroll
            for (int rr = 0; rr < 4; ++rr) {
                int p = mm * 16 + (lane >> 4) * 4 + rr;
                Pb[(size_t)p * 256 + o] = acc[mm][nn][rr];
            }
        }
}

// ---------------------------------------------------------------------------
// Reduce: out = P0+P1+P2+P3 + bias, scattered to out[ni][o][ii][jj].
// grid (cnt/64, 2): block handles 64 paths x 128 outputs; float4 stores.
// ---------------------------------------------------------------------------
__global__ __launch_bounds__(256) void reduce_kernel(const float* __restrict__ P,
                                                     const float* __restrict__ b,
                                                     float* __restrict__ out,
                                                     int chunk_alloc, int r_start)
{
    const int mb = blockIdx.x;
    const int pbase = r_start + mb * 64;
    const int ii = pbase >> 9;
    const int jj0 = (pbase >> 3) & 63;
    const int t = threadIdx.x;
    const int ol = t >> 1, hh = t & 1;

    const float* P0 = P + (size_t)mb * 64 * 256;
    const size_t ps = (size_t)chunk_alloc * 256;

    int o = blockIdx.y * 128 + ol;
    float bo = b[o];
    #pragma unroll
    for (int c = 0; c < 4; ++c) {
        int ni = hh * 4 + c;
        float v[8];
        #pragma unroll
        for (int qq = 0; qq < 8; ++qq) {
            size_t idx = (size_t)(qq * 8 + ni) * 256 + o;
            v[qq] = P0[idx] + P0[idx + ps] + P0[idx + 2 * ps] + P0[idx + 3 * ps] + bo;
        }
        float* dst = out + (size_t)(ni * 256 + o) * 1600 + ii * 64 + jj0;
        *reinterpret_cast<float4*>(dst)     = make_float4(v[0], v[1], v[2], v[3]);
        *reinterpret_cast<float4*>(dst + 4) = make_float4(v[4], v[5], v[6], v[7]);
    }
}

// ---------------------------------------------------------------------------
extern "C" void kernel_launch(void* const* d_in, const int* in_sizes, int n_in,
                              void* d_out, int out_size, void* d_ws, size_t ws_size,
                              hipStream_t stream)
{
    const float* x = (const float*)d_in[0];
    const float* W = (const float*)d_in[1];
    const float* b = (const float*)d_in[2];
    float* out = (float*)d_out;

    char* ws = (char*)d_ws;
    __hip_bfloat16* Wh = (__hip_bfloat16*)ws;
    __hip_bfloat16* Wl = Wh + (size_t)16 * NKT * 512;
    size_t a_off = (((size_t)16 * NKT * 512 * 2 * 2) + 255) & ~(size_t)255;

    // per-chunk bytes/path: A hi/lo (KPAD*2*2 = 9728) + P fp32 (4*256*4 = 4096)
    size_t avail = (ws_size > a_off) ? ws_size - a_off : 0;
    long long maxp = (long long)(avail / ((size_t)KPAD * 4 + 4096));
    int chunk = (int)((maxp / 64) * 64);
    if (chunk > NPATH) chunk = NPATH;
    if (chunk < 64) chunk = 64;

    __hip_bfloat16* Ah = (__hip_bfloat16*)(ws + a_off);
    __hip_bfloat16* Al_ = Ah + (size_t)chunk * KPAD;
    float* P = (float*)(Al_ + (size_t)chunk * KPAD);

    wconv_kernel<<<dim3(10, 256), 256, 0, stream>>>(W, Wh, Wl);

    for (int r0 = 0; r0 < NPATH; r0 += chunk) {
        int cnt = NPATH - r0;
        if (cnt > chunk) cnt = chunk;
        int nmblk = cnt / 64;
        int nblk = ((nmblk + 1) / 2) * 8;
        sig_kernel<<<dim3(cnt / 16), 256, 0, stream>>>(x, Ah, Al_, r0);
        gemm_kernel<<<dim3(nblk), 256, 0, stream>>>(Ah, Al_, Wh, Wl, P, chunk, nmblk);
        reduce_kernel<<<dim3(cnt / 64, 2), 256, 0, stream>>>(P, b, out, chunk, r0);
    }
}

// Round 10
// 125.793 us; speedup vs baseline: 1.3351x; 1.3351x over previous
//
#include <hip/hip_runtime.h>
#include <hip/hip_bf16.h>

typedef float f32x4 __attribute__((ext_vector_type(4)));
typedef short s16x8 __attribute__((ext_vector_type(8)));

#define SIGC 2379
#define KPAD 2432
#define NKT  76          // KPAD/32 k-tiles
#define NKT_HALF 38      // per split-K half
#define SROW 2440        // padded LDS row
#define NPATH 12800

// Tiled layout for A and W (bf16): element (row r, k) lives at
//   ((r>>4)*NKT + (k>>5))*512 + ((k>>3)&3)*128 + (r&15)*8 + (k&7)
// 1KB tiles of [ks(4)][R(16)][kw(8)] — fragment-ready for 16x16x32 MFMA
// (per-lane frag offset = lane*16B, lane-linear), stageable with one
// lane-linear global_load_lds per tile.

__device__ inline void split2(float v, __hip_bfloat16* h, __hip_bfloat16* l) {
    __hip_bfloat16 hh = __float2bfloat16(v);
    *h = hh;
    *l = __float2bfloat16(v - __bfloat162float(hh));
}

__device__ inline void gload_lds16(const __hip_bfloat16* g, __hip_bfloat16* l) {
    __builtin_amdgcn_global_load_lds(
        (const __attribute__((address_space(1))) void*)g,
        (__attribute__((address_space(3))) void*)l,
        16, 0, 0);
}

// ---------------------------------------------------------------------------
// W convert: W[256][2379] fp32 -> tiled Wh/Wl bf16 hi+lo (pad zeroed)
// ---------------------------------------------------------------------------
__global__ __launch_bounds__(256) void wconv_kernel(const float* __restrict__ W,
                                                    __hip_bfloat16* __restrict__ Wh,
                                                    __hip_bfloat16* __restrict__ Wl)
{
    int k = blockIdx.x * 256 + threadIdx.x;
    int n = blockIdx.y;
    if (k >= KPAD) return;
    float v = (k < SIGC) ? W[(size_t)n * SIGC + k] : 0.0f;
    size_t off = ((size_t)(n >> 4) * NKT + (k >> 5)) * 512 + ((k >> 3) & 3) * 128 + (n & 15) * 8 + (k & 7);
    split2(v, &Wh[off], &Wl[off]);
}

// ---------------------------------------------------------------------------
// Signature kernel (proven, ~HBM-floor): 4 waves/block, 4 pp-phases;
// at phase pp wave w computes path row = pp*4 + w -> the 4 live rows are
// consecutive -> cooperative 64B-contiguous copy-out. Register-only Chen
// scan; lane owns pairs p in {lane, lane+64, lane+128(<169)}.
// s3[ijk] += dx[k] * (s2[ij] + 0.5*dx[j]*(s1[i] + dx[i]/3))
// ---------------------------------------------------------------------------
__global__ __launch_bounds__(256) void sig_kernel(const float* __restrict__ x,
                                                  __hip_bfloat16* __restrict__ Ah,
                                                  __hip_bfloat16* __restrict__ Al_,
                                                  int r_start)
{
    __shared__ float inc_s[4][5][16];                        // [wave][step][channel]
    __shared__ __align__(16) __hip_bfloat16 hi_s[4][SROW];   // [wave] = row 4*pp+w
    __shared__ __align__(16) __hip_bfloat16 lo_s[4][SROW];

    const int t = threadIdx.x;
    const int w = t >> 6;
    const int lane = t & 63;

    const int p0 = lane;
    const int p1 = lane + 64;
    const int p2 = lane + 128;
    const bool has2 = (p2 < 169);
    const int i0 = p0 / 13, j0 = p0 - i0 * 13;
    const int i1 = p1 / 13, j1 = p1 - i1 * 13;
    const int i2 = p2 / 13, j2 = p2 - i2 * 13;   // used under has2

    for (int pp = 0; pp < 4; ++pp) {
        const int r = r_start + blockIdx.x * 16 + pp * 4 + w;
        const int nn = r & 7;
        const int jj = (r >> 3) & 63;
        const int ii = r >> 9;

        __syncthreads();   // guard inc_s / hi_s / lo_s reuse across pp
        if (lane < 13) {
            if (lane < 12) {
                const float* px = x + ((size_t)(nn * 12 + lane) * 1600 + ii * 64 + jj) * 5;
                float prev = 0.0f;
                #pragma unroll
                for (int l = 0; l < 5; ++l) {
                    float v = px[l];
                    inc_s[w][l][lane] = v - prev;
                    prev = v;
                }
            } else {
                inc_s[w][0][12] = 0.0f;
                #pragma unroll
                for (int l = 1; l < 5; ++l) inc_s[w][l][12] = 0.25f;
            }
        }
        __syncthreads();

        float s1i0 = 0.0f, s1i1 = 0.0f, s1i2 = 0.0f;
        float s2p0 = 0.0f, s2p1 = 0.0f, s2p2 = 0.0f;
        float s1own = 0.0f;
        float s3a[13], s3b[13], s3c[13];
        #pragma unroll
        for (int k = 0; k < 13; ++k) { s3a[k] = 0.0f; s3b[k] = 0.0f; s3c[k] = 0.0f; }

        for (int l = 0; l < 5; ++l) {
            float dxl[13];
            #pragma unroll
            for (int k = 0; k < 13; ++k) dxl[k] = inc_s[w][l][k];

            {   // pair 0
                float dxi = inc_s[w][l][i0];
                float dxj = inc_s[w][l][j0];
                float C   = s2p0 + 0.5f * dxj * (s1i0 + dxi * (1.0f / 3.0f));
                #pragma unroll
                for (int k = 0; k < 13; ++k) s3a[k] += dxl[k] * C;
                s2p0 += s1i0 * dxj + 0.5f * dxi * dxj;
                s1i0 += dxi;
            }
            {   // pair 1
                float dxi = inc_s[w][l][i1];
                float dxj = inc_s[w][l][j1];
                float C   = s2p1 + 0.5f * dxj * (s1i1 + dxi * (1.0f / 3.0f));
                #pragma unroll
                for (int k = 0; k < 13; ++k) s3b[k] += dxl[k] * C;
                s2p1 += s1i1 * dxj + 0.5f * dxi * dxj;
                s1i1 += dxi;
            }
            if (has2) {   // pair 2
                float dxi = inc_s[w][l][i2];
                float dxj = inc_s[w][l][j2];
                float C   = s2p2 + 0.5f * dxj * (s1i2 + dxi * (1.0f / 3.0f));
                #pragma unroll
                for (int k = 0; k < 13; ++k) s3c[k] += dxl[k] * C;
                s2p2 += s1i2 * dxj + 0.5f * dxi * dxj;
                s1i2 += dxi;
            }
            if (lane < 13) s1own += inc_s[w][l][lane];
        }

        // ---- write sig row into this wave's LDS row (hi/lo) ----
        if (lane < 13) split2(s1own, &hi_s[w][lane], &lo_s[w][lane]);
        split2(s2p0, &hi_s[w][13 + p0], &lo_s[w][13 + p0]);
        split2(s2p1, &hi_s[w][13 + p1], &lo_s[w][13 + p1]);
        if (has2) split2(s2p2, &hi_s[w][13 + p2], &lo_s[w][13 + p2]);
        #pragma unroll
        for (int k = 0; k < 13; ++k) split2(s3a[k], &hi_s[w][182 + p0 * 13 + k], &lo_s[w][182 + p0 * 13 + k]);
        #pragma unroll
        for (int k = 0; k < 13; ++k) split2(s3b[k], &hi_s[w][182 + p1 * 13 + k], &lo_s[w][182 + p1 * 13 + k]);
        if (has2) {
            #pragma unroll
            for (int k = 0; k < 13; ++k) split2(s3c[k], &hi_s[w][182 + p2 * 13 + k], &lo_s[w][182 + p2 * 13 + k]);
        }
        if (lane < KPAD - SIGC) {   // zero pad 2379..2431
            hi_s[w][SIGC + lane] = __float2bfloat16(0.0f);
            lo_s[w][SIGC + lane] = __float2bfloat16(0.0f);
        }

        __syncthreads();   // all 4 rows complete before cooperative copy-out

        // ---- block-cooperative coalesced copy-out (64B bursts) ----
        const int rtl = blockIdx.x;
        const int rr = t & 3, ks = (t >> 2) & 3, ts = t >> 4;
        #pragma unroll
        for (int it2 = 0; it2 < 5; ++it2) {
            int kt = it2 * 16 + ts;
            if (kt < NKT) {
                size_t off = ((size_t)rtl * NKT + kt) * 512 + ks * 128 + (pp * 4 + rr) * 8;
                int lidx = kt * 32 + ks * 8;
                *reinterpret_cast<int4*>(Ah + off)  = *reinterpret_cast<const int4*>(&hi_s[rr][lidx]);
                *reinterpret_cast<int4*>(Al_ + off) = *reinterpret_cast<const int4*>(&lo_s[rr][lidx]);
            }
        }
    }
}

// ---------------------------------------------------------------------------
// Split-bf16 GEMM, BM=128 x BN=128, split-K=2, COUNTED-VMCNT PIPELINE:
// P[ksp][m][o] = sum_{k in half} AhWh + AhWl + AlWh   (fp32 partials)
// Triple-buffered LDS (3 x 32KB), depth-2 prefetch: stage(kt+2) issued at
// iter kt; 's_waitcnt vmcnt(16)' (2 younger stages x 8 loads/wave stay in
// flight ACROSS the raw s_barrier) — the T3/T4 counted-wait, avoiding the
// 2-phase vmcnt(0) drain that capped r5/r7 at MfmaUtil 30%.
// 4 waves 2m x 2n, wave tile 64x64 = 4x4 frags (48 MFMA : 16 ds_read).
// bid = q*32 + ksp*16 + h*8 + x8, mIdx = q*8+x8 -> the 4 blocks of an
// m-block share bid%8 (same XCD slot): A's reuse served by L2.
// ---------------------------------------------------------------------------
__global__ __launch_bounds__(256) void gemm_kernel(const __hip_bfloat16* __restrict__ Ah,
                                                   const __hip_bfloat16* __restrict__ Al_,
                                                   const __hip_bfloat16* __restrict__ Wh,
                                                   const __hip_bfloat16* __restrict__ Wl,
                                                   float* __restrict__ P,
                                                   int chunk_alloc, int nmblk)
{
    // per buffer 32 tiles: [0-7]=Ah rows, [8-15]=Al, [16-23]=Wh cols, [24-31]=Wl
    __shared__ __align__(16) __hip_bfloat16 L[3][32 * 512];   // 96 KB

    const int bid = blockIdx.x;
    const int x8 = bid & 7;
    const int h = (bid >> 3) & 1;
    const int ksp = (bid >> 4) & 1;
    const int q = bid >> 5;
    const int mIdx = q * 8 + x8;
    if (mIdx >= nmblk) return;

    const int t = threadIdx.x;
    const int lane = t & 63;
    const int w = t >> 6;
    const int wm = w >> 1, wn = w & 1;
    const int rt0 = mIdx * 8;      // 8 m-row-tiles (128 rows)
    const int nt0 = h * 8;         // 8 n-row-tiles (128 cols)
    const int kt0 = ksp * NKT_HALF;

    f32x4 acc[4][4] = {};

    // wave w stages tiles w*8..w*8+7 (8 gload_lds per wave per stage)
    auto stage = [&](int buf, int kt) {
        #pragma unroll
        for (int s = 0; s < 8; ++s) {
            int tt = w * 8 + s;
            const __hip_bfloat16* g;
            if (tt < 8)       g = Ah  + ((size_t)(rt0 + tt)       * NKT + kt) * 512;
            else if (tt < 16) g = Al_ + ((size_t)(rt0 + tt - 8)   * NKT + kt) * 512;
            else if (tt < 24) g = Wh  + ((size_t)(nt0 + tt - 16)  * NKT + kt) * 512;
            else              g = Wl  + ((size_t)(nt0 + tt - 24)  * NKT + kt) * 512;
            gload_lds16(g + lane * 8, &L[buf][tt * 512]);
        }
    };

    auto compute = [&](int lb) {
        const __hip_bfloat16* Lb = &L[lb][0];
        s16x8 ah[4], al4[4], bh[4], bl4[4];
        #pragma unroll
        for (int mm = 0; mm < 4; ++mm) {
            ah[mm]  = *reinterpret_cast<const s16x8*>(&Lb[(wm * 4 + mm) * 512 + lane * 8]);
            al4[mm] = *reinterpret_cast<const s16x8*>(&Lb[(8 + wm * 4 + mm) * 512 + lane * 8]);
        }
        #pragma unroll
        for (int nn = 0; nn < 4; ++nn) {
            bh[nn]  = *reinterpret_cast<const s16x8*>(&Lb[(16 + wn * 4 + nn) * 512 + lane * 8]);
            bl4[nn] = *reinterpret_cast<const s16x8*>(&Lb[(24 + wn * 4 + nn) * 512 + lane * 8]);
        }
        __builtin_amdgcn_s_setprio(1);
        #pragma unroll
        for (int nn = 0; nn < 4; ++nn)
            #pragma unroll
            for (int mm = 0; mm < 4; ++mm) {
                acc[mm][nn] = __builtin_amdgcn_mfma_f32_16x16x32_bf16(ah[mm],  bh[nn],  acc[mm][nn], 0, 0, 0);
                acc[mm][nn] = __builtin_amdgcn_mfma_f32_16x16x32_bf16(ah[mm],  bl4[nn], acc[mm][nn], 0, 0, 0);
                acc[mm][nn] = __builtin_amdgcn_mfma_f32_16x16x32_bf16(al4[mm], bh[nn],  acc[mm][nn], 0, 0, 0);
            }
        __builtin_amdgcn_s_setprio(0);
    };

    stage(0, kt0);
    stage(1, kt0 + 1);

    #pragma unroll 1
    for (int kk = 0; kk < NKT_HALF; ++kk) {
        if (kk + 2 < NKT_HALF) stage((kk + 2) % 3, kt0 + kk + 2);
        // counted wait: oldest stage (tile kk) complete; 2 younger stay in flight
        if (kk + 2 < NKT_HALF)      asm volatile("s_waitcnt vmcnt(16)" ::: "memory");
        else if (kk + 1 < NKT_HALF) asm volatile("s_waitcnt vmcnt(8)" ::: "memory");
        else                        asm volatile("s_waitcnt vmcnt(0)" ::: "memory");
        __builtin_amdgcn_s_barrier();
        asm volatile("" ::: "memory");
        compute(kk % 3);
        asm volatile("" ::: "memory");
        __builtin_amdgcn_s_barrier();   // all reads of buf kk%3 done before overwrite
    }

    // ---- epilogue: coalesced fp32 partial stores ----
    // C/D layout: col=lane&15, row=(lane>>4)*4+reg
    float* Pb = P + ((size_t)ksp * chunk_alloc + mIdx * 128) * 256 + h * 128;
    #pragma unroll
    for (int mm = 0; mm < 4; ++mm)
        #pragma unroll
        for (int nn = 0; nn < 4; ++nn) {
            int o = wn * 64 + nn * 16 + (lane & 15);
            #pragma unroll
            for (int rr = 0; rr < 4; ++rr) {
                int p = wm * 64 + mm * 16 + (lane >> 4) * 4 + rr;
                Pb[(size_t)p * 256 + o] = acc[mm][nn][rr];
            }
        }
}

// ---------------------------------------------------------------------------
// Reduce: out = P0 + P1 + bias, scattered to out[ni][o][ii][jj].
// grid (cnt/64, 2): block handles 64 paths x 128 outputs; float4 stores.
// ---------------------------------------------------------------------------
__global__ __launch_bounds__(256) void reduce_kernel(const float* __restrict__ P,
                                                     const float* __restrict__ b,
                                                     float* __restrict__ out,
                                                     int chunk_alloc, int r_start)
{
    const int mb = blockIdx.x;
    const int pbase = r_start + mb * 64;
    const int ii = pbase >> 9;
    const int jj0 = (pbase >> 3) & 63;
    const int t = threadIdx.x;
    const int ol = t >> 1, hh = t & 1;

    const float* P0 = P + (size_t)mb * 64 * 256;
    const size_t ps = (size_t)chunk_alloc * 256;

    int o = blockIdx.y * 128 + ol;
    float bo = b[o];
    #pragma unroll
    for (int c = 0; c < 4; ++c) {
        int ni = hh * 4 + c;
        float v[8];
        #pragma unroll
        for (int qq = 0; qq < 8; ++qq) {
            size_t idx = (size_t)(qq * 8 + ni) * 256 + o;
            v[qq] = P0[idx] + P0[idx + ps] + bo;
        }
        float* dst = out + (size_t)(ni * 256 + o) * 1600 + ii * 64 + jj0;
        *reinterpret_cast<float4*>(dst)     = make_float4(v[0], v[1], v[2], v[3]);
        *reinterpret_cast<float4*>(dst + 4) = make_float4(v[4], v[5], v[6], v[7]);
    }
}

// ---------------------------------------------------------------------------
extern "C" void kernel_launch(void* const* d_in, const int* in_sizes, int n_in,
                              void* d_out, int out_size, void* d_ws, size_t ws_size,
                              hipStream_t stream)
{
    const float* x = (const float*)d_in[0];
    const float* W = (const float*)d_in[1];
    const float* b = (const float*)d_in[2];
    float* out = (float*)d_out;

    char* ws = (char*)d_ws;
    __hip_bfloat16* Wh = (__hip_bfloat16*)ws;
    __hip_bfloat16* Wl = Wh + (size_t)16 * NKT * 512;
    size_t a_off = (((size_t)16 * NKT * 512 * 2 * 2) + 255) & ~(size_t)255;

    // per-chunk bytes/path: A hi/lo (KPAD*2*2 = 9728) + P fp32 (2*256*4 = 2048)
    size_t avail = (ws_size > a_off) ? ws_size - a_off : 0;
    long long maxp = (long long)(avail / ((size_t)KPAD * 4 + 2048));
    int chunk = (int)((maxp / 128) * 128);
    if (chunk > NPATH) chunk = NPATH;
    if (chunk < 128) chunk = 128;

    __hip_bfloat16* Ah = (__hip_bfloat16*)(ws + a_off);
    __hip_bfloat16* Al_ = Ah + (size_t)chunk * KPAD;
    float* P = (float*)(Al_ + (size_t)chunk * KPAD);

    wconv_kernel<<<dim3(10, 256), 256, 0, stream>>>(W, Wh, Wl);

    for (int r0 = 0; r0 < NPATH; r0 += chunk) {
        int cnt = NPATH - r0;
        if (cnt > chunk) cnt = chunk;
        int nmblk = cnt / 128;
        int nblk = ((nmblk + 7) / 8) * 32;
        sig_kernel<<<dim3(cnt / 16), 256, 0, stream>>>(x, Ah, Al_, r0);
        gemm_kernel<<<dim3(nblk), 256, 0, stream>>>(Ah, Al_, Wh, Wl, P, chunk, nmblk);
        reduce_kernel<<<dim3(cnt / 64, 2), 256, 0, stream>>>(P, b, out, chunk, r0);
    }
}

// Round 11
// 112.983 us; speedup vs baseline: 1.4865x; 1.1134x over previous
//
#include <hip/hip_runtime.h>
#include <hip/hip_bf16.h>

typedef float f32x4 __attribute__((ext_vector_type(4)));
typedef short s16x8 __attribute__((ext_vector_type(8)));

#define SIGC 2379
#define KPAD 2432
#define NKT  76          // KPAD/32 k-tiles
#define SROW 2440        // padded LDS row
#define NPATH 12800

// Tiled layout for A and W (bf16): element (row r, k) lives at
//   ((r>>4)*NKT + (k>>5))*512 + ((k>>3)&3)*128 + (r&15)*8 + (k&7)
// 1KB tiles of [ks(4)][R(16)][kw(8)] — fragment-ready for 16x16x32 MFMA
// (per-lane frag offset = lane*16B, lane-linear), one lane-linear
// global_load_lds per tile.

__device__ inline void split2(float v, __hip_bfloat16* h, __hip_bfloat16* l) {
    __hip_bfloat16 hh = __float2bfloat16(v);
    *h = hh;
    *l = __float2bfloat16(v - __bfloat162float(hh));
}

__device__ inline void gload_lds16(const __hip_bfloat16* g, __hip_bfloat16* l) {
    __builtin_amdgcn_global_load_lds(
        (const __attribute__((address_space(1))) void*)g,
        (__attribute__((address_space(3))) void*)l,
        16, 0, 0);
}

// ---------------------------------------------------------------------------
// W convert: W[256][2379] fp32 -> tiled Wh/Wl bf16 hi+lo (pad zeroed)
// ---------------------------------------------------------------------------
__global__ __launch_bounds__(256) void wconv_kernel(const float* __restrict__ W,
                                                    __hip_bfloat16* __restrict__ Wh,
                                                    __hip_bfloat16* __restrict__ Wl)
{
    int k = blockIdx.x * 256 + threadIdx.x;
    int n = blockIdx.y;
    if (k >= KPAD) return;
    float v = (k < SIGC) ? W[(size_t)n * SIGC + k] : 0.0f;
    size_t off = ((size_t)(n >> 4) * NKT + (k >> 5)) * 512 + ((k >> 3) & 3) * 128 + (n & 15) * 8 + (k & 7);
    split2(v, &Wh[off], &Wl[off]);
}

// ---------------------------------------------------------------------------
// Signature kernel (proven): 4 waves/block, 4 pp-phases; at phase pp wave w
// computes path row = pp*4 + w -> 4 consecutive live rows -> cooperative
// 64B-contiguous copy-out. Register-only Chen scan; lane owns pairs
// p in {lane, lane+64, lane+128(<169)}.
// s3[ijk] += dx[k] * (s2[ij] + 0.5*dx[j]*(s1[i] + dx[i]/3))
// ---------------------------------------------------------------------------
__global__ __launch_bounds__(256) void sig_kernel(const float* __restrict__ x,
                                                  __hip_bfloat16* __restrict__ Ah,
                                                  __hip_bfloat16* __restrict__ Al_,
                                                  int r_start)
{
    __shared__ float inc_s[4][5][16];                        // [wave][step][channel]
    __shared__ __align__(16) __hip_bfloat16 hi_s[4][SROW];   // [wave] = row 4*pp+w
    __shared__ __align__(16) __hip_bfloat16 lo_s[4][SROW];

    const int t = threadIdx.x;
    const int w = t >> 6;
    const int lane = t & 63;

    const int p0 = lane;
    const int p1 = lane + 64;
    const int p2 = lane + 128;
    const bool has2 = (p2 < 169);
    const int i0 = p0 / 13, j0 = p0 - i0 * 13;
    const int i1 = p1 / 13, j1 = p1 - i1 * 13;
    const int i2 = p2 / 13, j2 = p2 - i2 * 13;   // used under has2

    for (int pp = 0; pp < 4; ++pp) {
        const int r = r_start + blockIdx.x * 16 + pp * 4 + w;
        const int nn = r & 7;
        const int jj = (r >> 3) & 63;
        const int ii = r >> 9;

        __syncthreads();   // guard inc_s / hi_s / lo_s reuse across pp
        if (lane < 13) {
            if (lane < 12) {
                const float* px = x + ((size_t)(nn * 12 + lane) * 1600 + ii * 64 + jj) * 5;
                float prev = 0.0f;
                #pragma unroll
                for (int l = 0; l < 5; ++l) {
                    float v = px[l];
                    inc_s[w][l][lane] = v - prev;
                    prev = v;
                }
            } else {
                inc_s[w][0][12] = 0.0f;
                #pragma unroll
                for (int l = 1; l < 5; ++l) inc_s[w][l][12] = 0.25f;
            }
        }
        __syncthreads();

        float s1i0 = 0.0f, s1i1 = 0.0f, s1i2 = 0.0f;
        float s2p0 = 0.0f, s2p1 = 0.0f, s2p2 = 0.0f;
        float s1own = 0.0f;
        float s3a[13], s3b[13], s3c[13];
        #pragma unroll
        for (int k = 0; k < 13; ++k) { s3a[k] = 0.0f; s3b[k] = 0.0f; s3c[k] = 0.0f; }

        for (int l = 0; l < 5; ++l) {
            float dxl[13];
            #pragma unroll
            for (int k = 0; k < 13; ++k) dxl[k] = inc_s[w][l][k];

            {   // pair 0
                float dxi = inc_s[w][l][i0];
                float dxj = inc_s[w][l][j0];
                float C   = s2p0 + 0.5f * dxj * (s1i0 + dxi * (1.0f / 3.0f));
                #pragma unroll
                for (int k = 0; k < 13; ++k) s3a[k] += dxl[k] * C;
                s2p0 += s1i0 * dxj + 0.5f * dxi * dxj;
                s1i0 += dxi;
            }
            {   // pair 1
                float dxi = inc_s[w][l][i1];
                float dxj = inc_s[w][l][j1];
                float C   = s2p1 + 0.5f * dxj * (s1i1 + dxi * (1.0f / 3.0f));
                #pragma unroll
                for (int k = 0; k < 13; ++k) s3b[k] += dxl[k] * C;
                s2p1 += s1i1 * dxj + 0.5f * dxi * dxj;
                s1i1 += dxi;
            }
            if (has2) {   // pair 2
                float dxi = inc_s[w][l][i2];
                float dxj = inc_s[w][l][j2];
                float C   = s2p2 + 0.5f * dxj * (s1i2 + dxi * (1.0f / 3.0f));
                #pragma unroll
                for (int k = 0; k < 13; ++k) s3c[k] += dxl[k] * C;
                s2p2 += s1i2 * dxj + 0.5f * dxi * dxj;
                s1i2 += dxi;
            }
            if (lane < 13) s1own += inc_s[w][l][lane];
        }

        // ---- write sig row into this wave's LDS row (hi/lo) ----
        if (lane < 13) split2(s1own, &hi_s[w][lane], &lo_s[w][lane]);
        split2(s2p0, &hi_s[w][13 + p0], &lo_s[w][13 + p0]);
        split2(s2p1, &hi_s[w][13 + p1], &lo_s[w][13 + p1]);
        if (has2) split2(s2p2, &hi_s[w][13 + p2], &lo_s[w][13 + p2]);
        #pragma unroll
        for (int k = 0; k < 13; ++k) split2(s3a[k], &hi_s[w][182 + p0 * 13 + k], &lo_s[w][182 + p0 * 13 + k]);
        #pragma unroll
        for (int k = 0; k < 13; ++k) split2(s3b[k], &hi_s[w][182 + p1 * 13 + k], &lo_s[w][182 + p1 * 13 + k]);
        if (has2) {
            #pragma unroll
            for (int k = 0; k < 13; ++k) split2(s3c[k], &hi_s[w][182 + p2 * 13 + k], &lo_s[w][182 + p2 * 13 + k]);
        }
        if (lane < KPAD - SIGC) {   // zero pad 2379..2431
            hi_s[w][SIGC + lane] = __float2bfloat16(0.0f);
            lo_s[w][SIGC + lane] = __float2bfloat16(0.0f);
        }

        __syncthreads();   // all 4 rows complete before cooperative copy-out

        // ---- block-cooperative coalesced copy-out (64B bursts) ----
        const int rtl = blockIdx.x;
        const int rr = t & 3, ks = (t >> 2) & 3, ts = t >> 4;
        #pragma unroll
        for (int it2 = 0; it2 < 5; ++it2) {
            int kt = it2 * 16 + ts;
            if (kt < NKT) {
                size_t off = ((size_t)rtl * NKT + kt) * 512 + ks * 128 + (pp * 4 + rr) * 8;
                int lidx = kt * 32 + ks * 8;
                *reinterpret_cast<int4*>(Ah + off)  = *reinterpret_cast<const int4*>(&hi_s[rr][lidx]);
                *reinterpret_cast<int4*>(Al_ + off) = *reinterpret_cast<const int4*>(&lo_s[rr][lidx]);
            }
        }
    }
}

// ---------------------------------------------------------------------------
// Split-bf16 GEMM, BM=128 x BN=128, NO splitK, counted-vmcnt depth-2 pipeline:
// out[m][o] = bias[o] + sum_k (AhWh + AhWl + AlWh)
// 3 LDS buffers x 32KB (32 tiles: 0-7 Ah, 8-15 Al, 16-23 Wh, 24-31 Wl);
// stage(kt+2) issued at iter kt; raw s_barrier + s_waitcnt vmcnt(16)
// keeps the 2 younger stages (2x8 loads/wave) in flight ACROSS barriers.
// 4 waves 2m x 2n, wave tile 64x64 = 4x4 frags (48 MFMA : 16 ds_read).
// bid = q*16 + h*8 + x8, mIdx = q*8+x8 -> both n-halves of an m-block share
// bid%8 (same XCD slot): A's 2nd read served by that XCD's L2.
// Epilogue: LDS fp32 transpose (stride 132) -> coalesced float4 direct-out
// stores with fused bias (16 consecutive jj per (ni,o)).
// ---------------------------------------------------------------------------
__global__ __launch_bounds__(256) void gemm_kernel(const __hip_bfloat16* __restrict__ Ah,
                                                   const __hip_bfloat16* __restrict__ Al_,
                                                   const __hip_bfloat16* __restrict__ Wh,
                                                   const __hip_bfloat16* __restrict__ Wl,
                                                   const float* __restrict__ b,
                                                   float* __restrict__ out,
                                                   int r_start, int nmblk)
{
    __shared__ __align__(16) __hip_bfloat16 L[3][32 * 512];   // 96 KB

    const int bid = blockIdx.x;
    const int x8 = bid & 7;
    const int h = (bid >> 3) & 1;
    const int q = bid >> 4;
    const int mIdx = q * 8 + x8;
    if (mIdx >= nmblk) return;

    const int t = threadIdx.x;
    const int lane = t & 63;
    const int w = t >> 6;
    const int wm = w >> 1, wn = w & 1;
    const int rt0 = mIdx * 8;      // 8 m-row-tiles (128 paths)
    const int nt0 = h * 8;         // 8 n-row-tiles (128 outputs)

    f32x4 acc[4][4] = {};

    // wave w stages tiles w*8..w*8+7 (8 gload_lds per wave per stage)
    auto stage = [&](int buf, int kt) {
        #pragma unroll
        for (int s = 0; s < 8; ++s) {
            int tt = w * 8 + s;
            const __hip_bfloat16* g;
            if (tt < 8)       g = Ah  + ((size_t)(rt0 + tt)       * NKT + kt) * 512;
            else if (tt < 16) g = Al_ + ((size_t)(rt0 + tt - 8)   * NKT + kt) * 512;
            else if (tt < 24) g = Wh  + ((size_t)(nt0 + tt - 16)  * NKT + kt) * 512;
            else              g = Wl  + ((size_t)(nt0 + tt - 24)  * NKT + kt) * 512;
            gload_lds16(g + lane * 8, &L[buf][tt * 512]);
        }
    };

    auto compute = [&](int lb) {
        const __hip_bfloat16* Lb = &L[lb][0];
        s16x8 ah[4], al4[4], bh[4], bl4[4];
        #pragma unroll
        for (int mm = 0; mm < 4; ++mm) {
            ah[mm]  = *reinterpret_cast<const s16x8*>(&Lb[(wm * 4 + mm) * 512 + lane * 8]);
            al4[mm] = *reinterpret_cast<const s16x8*>(&Lb[(8 + wm * 4 + mm) * 512 + lane * 8]);
        }
        #pragma unroll
        for (int nn = 0; nn < 4; ++nn) {
            bh[nn]  = *reinterpret_cast<const s16x8*>(&Lb[(16 + wn * 4 + nn) * 512 + lane * 8]);
            bl4[nn] = *reinterpret_cast<const s16x8*>(&Lb[(24 + wn * 4 + nn) * 512 + lane * 8]);
        }
        __builtin_amdgcn_s_setprio(1);
        #pragma unroll
        for (int nn = 0; nn < 4; ++nn)
            #pragma unroll
            for (int mm = 0; mm < 4; ++mm) {
                acc[mm][nn] = __builtin_amdgcn_mfma_f32_16x16x32_bf16(ah[mm],  bh[nn],  acc[mm][nn], 0, 0, 0);
                acc[mm][nn] = __builtin_amdgcn_mfma_f32_16x16x32_bf16(ah[mm],  bl4[nn], acc[mm][nn], 0, 0, 0);
                acc[mm][nn] = __builtin_amdgcn_mfma_f32_16x16x32_bf16(al4[mm], bh[nn],  acc[mm][nn], 0, 0, 0);
            }
        __builtin_amdgcn_s_setprio(0);
    };

    stage(0, 0);
    stage(1, 1);
    int b0 = 0, b1 = 1, b2 = 2;

    #pragma unroll 1
    for (int kt = 0; kt < NKT; ++kt) {
        if (kt + 2 < NKT) {
            stage(b2, kt + 2);
            asm volatile("s_waitcnt vmcnt(16)" ::: "memory");   // drain stage kt only
        } else if (kt + 1 < NKT) {
            asm volatile("s_waitcnt vmcnt(8)" ::: "memory");
        } else {
            asm volatile("s_waitcnt vmcnt(0)" ::: "memory");
        }
        __builtin_amdgcn_s_barrier();
        compute(b0);
        __builtin_amdgcn_s_barrier();   // all reads of b0 done before its overwrite
        int tmp = b0; b0 = b1; b1 = b2; b2 = tmp;
    }

    // ---- epilogue: fp32 transpose through LDS, coalesced direct-out ----
    __syncthreads();
    float* T = (float*)&L[0][0];   // 128 x 132 fp32 = 67.6 KB (fits in 96 KB)
    #pragma unroll
    for (int mm = 0; mm < 4; ++mm)
        #pragma unroll
        for (int nn = 0; nn < 4; ++nn)
            #pragma unroll
            for (int rr = 0; rr < 4; ++rr) {
                int p = wm * 64 + mm * 16 + (lane >> 4) * 4 + rr;
                int o = wn * 64 + nn * 16 + (lane & 15);
                T[p * 132 + o] = acc[mm][nn][rr];
            }
    __syncthreads();

    const int pbase = r_start + mIdx * 128;
    const int ii = pbase >> 9;
    const int jj0 = (pbase >> 3) & 63;     // multiple of 16
    const int ol = t >> 1, hh = t & 1;
    const int o = h * 128 + ol;
    const float bo = b[o];
    #pragma unroll
    for (int c = 0; c < 4; ++c) {
        int ni = hh * 4 + c;
        float v[16];
        #pragma unroll
        for (int qq = 0; qq < 16; ++qq) v[qq] = T[(qq * 8 + ni) * 132 + ol] + bo;
        float* dst = out + (size_t)(ni * 256 + o) * 1600 + ii * 64 + jj0;
        *reinterpret_cast<float4*>(dst)      = make_float4(v[0],  v[1],  v[2],  v[3]);
        *reinterpret_cast<float4*>(dst + 4)  = make_float4(v[4],  v[5],  v[6],  v[7]);
        *reinterpret_cast<float4*>(dst + 8)  = make_float4(v[8],  v[9],  v[10], v[11]);
        *reinterpret_cast<float4*>(dst + 12) = make_float4(v[12], v[13], v[14], v[15]);
    }
}

// ---------------------------------------------------------------------------
extern "C" void kernel_launch(void* const* d_in, const int* in_sizes, int n_in,
                              void* d_out, int out_size, void* d_ws, size_t ws_size,
                              hipStream_t stream)
{
    const float* x = (const float*)d_in[0];
    const float* W = (const float*)d_in[1];
    const float* b = (const float*)d_in[2];
    float* out = (float*)d_out;

    char* ws = (char*)d_ws;
    __hip_bfloat16* Wh = (__hip_bfloat16*)ws;
    __hip_bfloat16* Wl = Wh + (size_t)16 * NKT * 512;
    size_t a_off = (((size_t)16 * NKT * 512 * 2 * 2) + 255) & ~(size_t)255;

    // per-path bytes: A hi/lo = KPAD*2*2 = 9728
    size_t avail = (ws_size > a_off) ? ws_size - a_off : 0;
    long long maxp = (long long)(avail / ((size_t)KPAD * 4));
    int chunk = (int)((maxp / 128) * 128);
    if (chunk > NPATH) chunk = NPATH;
    if (chunk < 128) chunk = 128;

    __hip_bfloat16* Ah = (__hip_bfloat16*)(ws + a_off);
    __hip_bfloat16* Al_ = Ah + (size_t)chunk * KPAD;

    wconv_kernel<<<dim3(10, 256), 256, 0, stream>>>(W, Wh, Wl);

    for (int r0 = 0; r0 < NPATH; r0 += chunk) {
        int cnt = NPATH - r0;
        if (cnt > chunk) cnt = chunk;
        int nmblk = cnt / 128;
        int nblk = ((nmblk + 7) / 8) * 16;
        sig_kernel<<<dim3(cnt / 16), 256, 0, stream>>>(x, Ah, Al_, r0);
        gemm_kernel<<<dim3(nblk), 256, 0, stream>>>(Ah, Al_, Wh, Wl, b, out, r0, nmblk);
    }
}